// Round 1
// baseline (785.916 us; speedup 1.0000x reference)
//
#include <hip/hip_runtime.h>

// Problem constants (match reference)
constexpr int N  = 100000;   // nodes
constexpr int E  = 1600000;  // edges
constexpr int H  = 128;      // hidden
constexpr int NB = 4096;     // root pairs
constexpr int HOPS = 3;

// ---------------- workspace layout (byte offsets, 256B aligned) ---------------
constexpr size_t ALIGN = 256;
constexpr size_t alup(size_t x) { return (x + ALIGN - 1) & ~(ALIGN - 1); }

constexpr size_t OFF_X       = 0;                                        // [N,128] f32
constexpr size_t OFF_SSRC    = alup(OFF_X + (size_t)N * H * 4);          // [3][N] f32
constexpr size_t OFF_SDST    = alup(OFF_SSRC + (size_t)3 * N * 4);       // [3][N] f32
constexpr size_t OFF_WVEC    = alup(OFF_SDST + (size_t)3 * N * 4);       // [6][128] f32
constexpr size_t OFF_SELMAP  = alup(OFF_WVEC + 6 * H * 4);               // [N] int
constexpr size_t OFF_NODELST = alup(OFF_SELMAP + (size_t)N * 4);         // [4096] int
constexpr size_t OFF_CNT     = alup(OFF_NODELST + NB * 4);               // [2] int (cnt, ecnt)
constexpr size_t OFF_CESRC   = alup(OFF_CNT + 256);                      // [E] int
constexpr size_t OFF_CEDST   = alup(OFF_CESRC + (size_t)E * 4);          // [E] int
constexpr size_t OFF_DEG     = alup(OFF_CEDST + (size_t)E * 4);          // [4096] int
constexpr size_t OFF_OFFS    = alup(OFF_DEG + NB * 4);                   // [4097] int
constexpr size_t OFF_CURSOR  = alup(OFF_OFFS + (NB + 1) * 4);            // [4096] int
constexpr size_t OFF_ESORT   = alup(OFF_CURSOR + NB * 4);                // [E] int
constexpr size_t OFF_AGGX    = alup(OFF_ESORT + (size_t)E * 4);          // [3][4096][128] f32
constexpr size_t OFF_HTMP    = alup(OFF_AGGX + (size_t)3 * NB * H * 4);  // [4096][128]
constexpr size_t OFF_XS      = alup(OFF_HTMP + (size_t)NB * H * 4);      // [4096][128]
constexpr size_t OFF_HBUF    = alup(OFF_XS + (size_t)NB * H * 4);        // [4096][128]
constexpr size_t OFF_CBUF    = alup(OFF_HBUF + (size_t)NB * H * 4);      // [4096][128]
constexpr size_t OFF_GATES   = alup(OFF_CBUF + (size_t)NB * H * 4);      // [4096][512]
constexpr size_t OFF_L2OUT   = alup(OFF_GATES + (size_t)NB * 512 * 4);   // [4096][128]

__device__ __forceinline__ float lrelu(float v) { return v > 0.f ? v : 0.2f * v; }
__device__ __forceinline__ float sigmoidf_(float v) { return 1.f / (1.f + __expf(-v)); }

// ---------------- tiny setup kernels -----------------------------------------

// wvec[i*2+0][k] = sum_j gat_W[i][k][j]*a_src[i][j]; +1 for a_dst
__global__ void wvec_kernel(const float* __restrict__ gat_W,
                            const float* __restrict__ a_src,
                            const float* __restrict__ a_dst,
                            float* __restrict__ wvec) {
  int i = blockIdx.x >> 1, which = blockIdx.x & 1;
  int k = threadIdx.x;
  __shared__ float av[H];
  av[k] = which ? a_dst[i * H + k] : a_src[i * H + k];
  __syncthreads();
  const float* Wr = gat_W + (size_t)i * H * H + (size_t)k * H;
  float s = 0.f;
  #pragma unroll 8
  for (int j = 0; j < H; j++) s = fmaf(Wr[j], av[j], s);
  wvec[(i * 2 + which) * H + k] = s;
}

__global__ void mark_roots(const int* __restrict__ root, const int* __restrict__ aggp,
                           int* __restrict__ sel_map) {
  int b = blockIdx.x * 256 + threadIdx.x;
  if (b >= NB) return;
  int node = root[2 * b + (aggp[0] ? 0 : 1)];
  sel_map[node] = -2;   // all writers write the same value: benign race
}

__global__ void assign_ids(int* __restrict__ sel_map, int* __restrict__ node_list,
                           int* __restrict__ cnt) {
  int n = blockIdx.x * 256 + threadIdx.x;
  if (n >= N) return;
  if (sel_map[n] == -2) {
    int c = atomicAdd(cnt, 1);
    sel_map[n] = c;
    node_list[c] = n;
  }
}

// ---------------- GEMM: 128x128 tile, 8x8 microtile (for lin1) ----------------
// A is two segments of [M,128] (concat along K); B two segments of [128,N].
__global__ __launch_bounds__(256)
void gemm128(const float* __restrict__ a0, const float* __restrict__ a1,
             const float* __restrict__ b0, const float* __restrict__ b1,
             const float* __restrict__ bias, float* __restrict__ Cc,
             int M, int Nn, int K) {
  __shared__ float As[16][132];
  __shared__ float Bs[16][128];
  const int t = threadIdx.x;
  const int row0 = blockIdx.y * 128;
  const int col0 = blockIdx.x * 128;
  const int tx = t & 15, ty = t >> 4;
  float acc[8][8];
  #pragma unroll
  for (int i = 0; i < 8; i++)
    #pragma unroll
    for (int j = 0; j < 8; j++) acc[i][j] = 0.f;

  const float* asegs[2] = {a0, a1};
  const float* bsegs[2] = {b0, b1};

  for (int k0 = 0; k0 < K; k0 += 16) {
    const float* abase = asegs[k0 >> 7] + (k0 & 127);
    const float* bbase = bsegs[k0 >> 7] + (size_t)(k0 & 127) * Nn + col0;
    #pragma unroll
    for (int l = 0; l < 2; l++) {
      int q = t + l * 256;
      int r = q >> 2;
      int kq = (q & 3) * 4;
      int gr = row0 + r;
      float4 v = make_float4(0.f, 0.f, 0.f, 0.f);
      if (gr < M) v = *(const float4*)(abase + (size_t)gr * H + kq);
      As[kq + 0][r] = v.x; As[kq + 1][r] = v.y; As[kq + 2][r] = v.z; As[kq + 3][r] = v.w;
    }
    #pragma unroll
    for (int l = 0; l < 2; l++) {
      int q = t + l * 256;
      int kk = q >> 5;
      int c = (q & 31) * 4;
      *(float4*)(&Bs[kk][c]) = *(const float4*)(bbase + (size_t)kk * Nn + c);
    }
    __syncthreads();
    #pragma unroll
    for (int kk = 0; kk < 16; kk++) {
      float ar[8], br[8];
      *(float4*)&ar[0] = *(const float4*)&As[kk][ty * 8];
      *(float4*)&ar[4] = *(const float4*)&As[kk][ty * 8 + 4];
      *(float4*)&br[0] = *(const float4*)&Bs[kk][tx * 8];
      *(float4*)&br[4] = *(const float4*)&Bs[kk][tx * 8 + 4];
      #pragma unroll
      for (int i = 0; i < 8; i++)
        #pragma unroll
        for (int j = 0; j < 8; j++) acc[i][j] = fmaf(ar[i], br[j], acc[i][j]);
    }
    __syncthreads();
  }
  #pragma unroll
  for (int i = 0; i < 8; i++) {
    int r = row0 + ty * 8 + i;
    if (r < M) {
      int cb = col0 + tx * 8;
      float* crow = Cc + (size_t)r * Nn + cb;
      float4 v0, v1;
      v0.x = acc[i][0] + bias[cb + 0]; v0.y = acc[i][1] + bias[cb + 1];
      v0.z = acc[i][2] + bias[cb + 2]; v0.w = acc[i][3] + bias[cb + 3];
      v1.x = acc[i][4] + bias[cb + 4]; v1.y = acc[i][5] + bias[cb + 5];
      v1.z = acc[i][6] + bias[cb + 6]; v1.w = acc[i][7] + bias[cb + 7];
      *(float4*)crow = v0;
      *(float4*)(crow + 4) = v1;
    }
  }
}

// ---------------- GEMM: 64x64 tile, 4x4 microtile (small GEMMs) ---------------
// A: up to 3 segments of [M,128] (concat along K). B: up to 3 segments of [128,N].
__global__ __launch_bounds__(256)
void gemm64(const float* __restrict__ a0, const float* __restrict__ a1,
            const float* __restrict__ a2,
            const float* __restrict__ b0, const float* __restrict__ b1,
            const float* __restrict__ b2,
            const float* __restrict__ bias, float* __restrict__ Cc,
            int M, int Nn, int K, int act) {
  __shared__ float As[16][68];
  __shared__ float Bs[16][64];
  const int t = threadIdx.x;
  const int row0 = blockIdx.y * 64;
  const int col0 = blockIdx.x * 64;
  const int tx = t & 15, ty = t >> 4;
  float acc[4][4];
  #pragma unroll
  for (int i = 0; i < 4; i++)
    #pragma unroll
    for (int j = 0; j < 4; j++) acc[i][j] = 0.f;

  const float* asegs[3] = {a0, a1, a2};
  const float* bsegs[3] = {b0, b1, b2};

  for (int k0 = 0; k0 < K; k0 += 16) {
    const float* abase = asegs[k0 >> 7] + (k0 & 127);
    const float* bbase = bsegs[k0 >> 7] + (size_t)(k0 & 127) * Nn + col0;
    {
      int r = t >> 2, kq = (t & 3) * 4;
      int gr = row0 + r;
      float4 v = make_float4(0.f, 0.f, 0.f, 0.f);
      if (gr < M) v = *(const float4*)(abase + (size_t)gr * H + kq);
      As[kq + 0][r] = v.x; As[kq + 1][r] = v.y; As[kq + 2][r] = v.z; As[kq + 3][r] = v.w;
      int kk = t >> 4, c = (t & 15) * 4;
      *(float4*)(&Bs[kk][c]) = *(const float4*)(bbase + (size_t)kk * Nn + c);
    }
    __syncthreads();
    #pragma unroll
    for (int kk = 0; kk < 16; kk++) {
      float4 a4 = *(const float4*)&As[kk][ty * 4];
      float4 b4 = *(const float4*)&Bs[kk][tx * 4];
      float ar[4] = {a4.x, a4.y, a4.z, a4.w};
      float br[4] = {b4.x, b4.y, b4.z, b4.w};
      #pragma unroll
      for (int i = 0; i < 4; i++)
        #pragma unroll
        for (int j = 0; j < 4; j++) acc[i][j] = fmaf(ar[i], br[j], acc[i][j]);
    }
    __syncthreads();
  }
  #pragma unroll
  for (int i = 0; i < 4; i++) {
    int r = row0 + ty * 4 + i;
    if (r < M) {
      int cb = col0 + tx * 4;
      float4 v;
      v.x = acc[i][0] + bias[cb + 0];
      v.y = acc[i][1] + bias[cb + 1];
      v.z = acc[i][2] + bias[cb + 2];
      v.w = acc[i][3] + bias[cb + 3];
      if (act == 1) { v.x = tanhf(v.x); v.y = tanhf(v.y); v.z = tanhf(v.z); v.w = tanhf(v.w); }
      *(float4*)(Cc + (size_t)r * Nn + cb) = v;
    }
  }
}

// ---------------- attention score vectors: s = x @ wvec ----------------------
__global__ __launch_bounds__(256)
void score_kernel(const float* __restrict__ x, const float* __restrict__ wvec,
                  float* __restrict__ s_src, float* __restrict__ s_dst) {
  int wv = blockIdx.x * 4 + (threadIdx.x >> 6);
  int lane = threadIdx.x & 63;
  if (wv >= N) return;
  float2 v = *(const float2*)(x + (size_t)wv * H + lane * 2);
  float acc[6];
  #pragma unroll
  for (int i = 0; i < 6; i++) {
    float2 w = *(const float2*)(wvec + i * H + lane * 2);
    acc[i] = v.x * w.x + v.y * w.y;
  }
  #pragma unroll
  for (int off = 32; off > 0; off >>= 1)
    #pragma unroll
    for (int i = 0; i < 6; i++) acc[i] += __shfl_down(acc[i], off);
  if (lane == 0) {
    #pragma unroll
    for (int i = 0; i < 3; i++) {
      s_src[i * N + wv] = acc[2 * i + 0];
      s_dst[i * N + wv] = acc[2 * i + 1];
    }
  }
}

// ---------------- edge compaction + CSR by destination ------------------------
__global__ void compact_edges(const int* __restrict__ ei, const int* __restrict__ sel_map,
                              int* __restrict__ ce_src, int* __restrict__ ce_dst,
                              int* __restrict__ ecnt, int* __restrict__ deg) {
  int e = blockIdx.x * 256 + threadIdx.x;
  if (e >= E) return;
  int dst = ei[E + e];
  int d = sel_map[dst];
  if (d >= 0) {
    int k = atomicAdd(ecnt, 1);
    ce_src[k] = ei[e];
    ce_dst[k] = d;
    atomicAdd(&deg[d], 1);
  }
}

__global__ __launch_bounds__(1024)
void scan_kernel(const int* __restrict__ deg, int* __restrict__ offs) {
  __shared__ int part[1024];
  int t = threadIdx.x;
  int base = t * 4;
  int v0 = deg[base], v1 = deg[base + 1], v2 = deg[base + 2], v3 = deg[base + 3];
  int s = v0 + v1 + v2 + v3;
  part[t] = s;
  __syncthreads();
  for (int off = 1; off < 1024; off <<= 1) {
    int tmp = (t >= off) ? part[t - off] : 0;
    __syncthreads();
    part[t] += tmp;
    __syncthreads();
  }
  int run = part[t] - s;  // exclusive prefix of this chunk
  offs[base] = run; run += v0;
  offs[base + 1] = run; run += v1;
  offs[base + 2] = run; run += v2;
  offs[base + 3] = run; run += v3;
  if (t == 1023) offs[NB] = part[1023];
}

__global__ void scatter_edges(const int* __restrict__ ce_src, const int* __restrict__ ce_dst,
                              const int* __restrict__ ecnt, const int* __restrict__ offs,
                              int* __restrict__ cursor, int* __restrict__ es_sorted) {
  int k = blockIdx.x * 256 + threadIdx.x;
  if (k >= ecnt[0]) return;
  int c = ce_dst[k];
  int p = atomicAdd(&cursor[c], 1);
  es_sorted[offs[c] + p] = ce_src[k];
}

// ---------------- per-destination GAT softmax aggregation ---------------------
// block = 128 threads = one selected node; thread = one feature.
__global__ __launch_bounds__(128)
void gat_node_kernel(const int* __restrict__ node_list, const int* __restrict__ cntp,
                     const int* __restrict__ offs, const int* __restrict__ es_sorted,
                     const float* __restrict__ x, const float* __restrict__ s_src,
                     const float* __restrict__ s_dst,
                     float* __restrict__ aggx, float* __restrict__ xsbuf) {
  int c = blockIdx.x;
  if (c >= cntp[0]) return;
  int t = threadIdx.x;
  int n = node_list[c];
  // stash xs0 = x at this node (compact)
  float xv = x[(size_t)n * H + t];
  xsbuf[(size_t)c * H + t] = xv;
  float sd0 = s_dst[0 * N + n], sd1 = s_dst[1 * N + n], sd2 = s_dst[2 * N + n];
  int e0 = offs[c], e1 = offs[c + 1];
  // pass 1: max score per hop (threads parallel over edges)
  float m0 = -1e30f, m1 = -1e30f, m2 = -1e30f;
  for (int e = e0 + t; e < e1; e += 128) {
    int s = es_sorted[e];
    m0 = fmaxf(m0, lrelu(s_src[0 * N + s] + sd0));
    m1 = fmaxf(m1, lrelu(s_src[1 * N + s] + sd1));
    m2 = fmaxf(m2, lrelu(s_src[2 * N + s] + sd2));
  }
  __shared__ float red[3][128];
  red[0][t] = m0; red[1][t] = m1; red[2][t] = m2;
  __syncthreads();
  for (int s2 = 64; s2 > 0; s2 >>= 1) {
    if (t < s2) {
      red[0][t] = fmaxf(red[0][t], red[0][t + s2]);
      red[1][t] = fmaxf(red[1][t], red[1][t + s2]);
      red[2][t] = fmaxf(red[2][t], red[2][t + s2]);
    }
    __syncthreads();
  }
  m0 = red[0][0]; m1 = red[1][0]; m2 = red[2][0];
  // pass 2: serial over edges, threads parallel over features
  float u0 = 0.f, u1 = 0.f, u2 = 0.f, z0 = 0.f, z1 = 0.f, z2 = 0.f;
  for (int e = e0; e < e1; e++) {
    int s = es_sorted[e];            // broadcast
    float xs = x[(size_t)s * H + t]; // coalesced 512B gather
    float ex0 = __expf(lrelu(s_src[0 * N + s] + sd0) - m0);
    float ex1 = __expf(lrelu(s_src[1 * N + s] + sd1) - m1);
    float ex2 = __expf(lrelu(s_src[2 * N + s] + sd2) - m2);
    z0 += ex0; z1 += ex1; z2 += ex2;
    u0 = fmaf(ex0, xs, u0); u1 = fmaf(ex1, xs, u1); u2 = fmaf(ex2, xs, u2);
  }
  size_t cb = (size_t)c * H + t;
  bool any = e1 > e0;
  aggx[0 * ((size_t)NB * H) + cb] = any ? u0 / z0 : 0.f;
  aggx[1 * ((size_t)NB * H) + cb] = any ? u1 / z1 : 0.f;
  aggx[2 * ((size_t)NB * H) + cb] = any ? u2 / z2 : 0.f;
}

// ---------------- LSTM gate nonlinearity --------------------------------------
__global__ void lstm_gate_kernel(const float* __restrict__ gates,
                                 float* __restrict__ cbuf, float* __restrict__ hbuf,
                                 float* __restrict__ xsbuf) {
  int id = blockIdx.x * 256 + threadIdx.x;
  if (id >= NB * H) return;
  int c = id >> 7, j = id & 127;
  const float* g = gates + (size_t)c * 512;
  float gi = g[j], gf = g[128 + j], gg = g[256 + j], go = g[384 + j];
  float cp = cbuf[id];
  float cn = sigmoidf_(gf) * cp + sigmoidf_(gi) * tanhf(gg);
  float hn = sigmoidf_(go) * tanhf(cn);
  cbuf[id] = cn;
  hbuf[id] = hn;
  xsbuf[id] = hn;
}

// ---------------- output gather ------------------------------------------------
__global__ void scatter_out(const float* __restrict__ l2out, const int* __restrict__ sel_map,
                            const int* __restrict__ root, const int* __restrict__ aggp,
                            float* __restrict__ out) {
  int id = blockIdx.x * 256 + threadIdx.x;
  if (id >= NB * H) return;
  int b = id >> 7, f = id & 127;
  int node = root[2 * b + (aggp[0] ? 0 : 1)];
  int c = sel_map[node];
  out[id] = l2out[(size_t)c * H + f];
}

// ==============================================================================
extern "C" void kernel_launch(void* const* d_in, const int* in_sizes, int n_in,
                              void* d_out, int out_size, void* d_ws, size_t ws_size,
                              hipStream_t stream) {
  const float* node_feat = (const float*)d_in[0];
  const float* send_embd = (const float*)d_in[1];
  const int*   edge_idx  = (const int*)d_in[2];
  const int*   root_idx  = (const int*)d_in[3];
  const int*   aggp      = (const int*)d_in[4];
  const float* lin1_W    = (const float*)d_in[5];
  const float* lin1_b    = (const float*)d_in[6];
  const float* gat_W     = (const float*)d_in[7];
  const float* gat_asrc  = (const float*)d_in[8];
  const float* gat_adst  = (const float*)d_in[9];
  const float* gat_b     = (const float*)d_in[10];
  const float* lstm_Wih  = (const float*)d_in[11];
  const float* lstm_Whh  = (const float*)d_in[12];
  const float* lstm_b    = (const float*)d_in[13];
  const float* lin2_W    = (const float*)d_in[14];
  const float* lin2_b    = (const float*)d_in[15];
  float* out = (float*)d_out;

  char* ws = (char*)d_ws;
  float* x       = (float*)(ws + OFF_X);
  float* s_src   = (float*)(ws + OFF_SSRC);
  float* s_dst   = (float*)(ws + OFF_SDST);
  float* wvec    = (float*)(ws + OFF_WVEC);
  int*   sel_map = (int*)(ws + OFF_SELMAP);
  int*   nodelst = (int*)(ws + OFF_NODELST);
  int*   cnt     = (int*)(ws + OFF_CNT);       // cnt[0]=nsel, cnt[1]=ecnt
  int*   ce_src  = (int*)(ws + OFF_CESRC);
  int*   ce_dst  = (int*)(ws + OFF_CEDST);
  int*   deg     = (int*)(ws + OFF_DEG);
  int*   offs    = (int*)(ws + OFF_OFFS);
  int*   cursor  = (int*)(ws + OFF_CURSOR);
  int*   esort   = (int*)(ws + OFF_ESORT);
  float* aggx    = (float*)(ws + OFF_AGGX);
  float* htmp    = (float*)(ws + OFF_HTMP);
  float* xsbuf   = (float*)(ws + OFF_XS);
  float* hbuf    = (float*)(ws + OFF_HBUF);
  float* cbuf    = (float*)(ws + OFF_CBUF);
  float* gates   = (float*)(ws + OFF_GATES);
  float* l2out   = (float*)(ws + OFF_L2OUT);

  // per-call init (ws is re-poisoned before every timed launch)
  hipMemsetAsync(sel_map, 0xFF, (size_t)N * 4, stream);   // -1
  hipMemsetAsync(cnt, 0, 256, stream);
  hipMemsetAsync(deg, 0, NB * 4, stream);
  hipMemsetAsync(cursor, 0, NB * 4, stream);
  hipMemsetAsync(hbuf, 0, (size_t)NB * H * 4, stream);
  hipMemsetAsync(cbuf, 0, (size_t)NB * H * 4, stream);

  wvec_kernel<<<6, 128, 0, stream>>>(gat_W, gat_asrc, gat_adst, wvec);
  mark_roots<<<(NB + 255) / 256, 256, 0, stream>>>(root_idx, aggp, sel_map);
  assign_ids<<<(N + 255) / 256, 256, 0, stream>>>(sel_map, nodelst, cnt);

  // lin1: x = [node_feat | send_embd] @ lin1_W + lin1_b   (M=N, N=128, K=256)
  gemm128<<<dim3(1, (N + 127) / 128), 256, 0, stream>>>(
      node_feat, send_embd, lin1_W, lin1_W + 128 * H, lin1_b, x, N, H, 256);

  score_kernel<<<(N + 3) / 4, 256, 0, stream>>>(x, wvec, s_src, s_dst);

  compact_edges<<<(E + 255) / 256, 256, 0, stream>>>(edge_idx, sel_map, ce_src, ce_dst,
                                                     cnt + 1, deg);
  scan_kernel<<<1, 1024, 0, stream>>>(deg, offs);
  scatter_edges<<<(E + 255) / 256, 256, 0, stream>>>(ce_src, ce_dst, cnt + 1, offs,
                                                     cursor, esort);
  gat_node_kernel<<<NB, 128, 0, stream>>>(nodelst, cnt, offs, esort, x, s_src, s_dst,
                                          aggx, xsbuf);

  for (int i = 0; i < HOPS; i++) {
    // h_tmp_i = tanh(aggx_i @ gat_W[i] + gat_b[i])   (M=4096,N=128,K=128)
    gemm64<<<dim3(2, NB / 64), 256, 0, stream>>>(
        aggx + (size_t)i * NB * H, nullptr, nullptr,
        gat_W + (size_t)i * H * H, nullptr, nullptr,
        gat_b + (size_t)i * H, htmp, NB, H, 128, 1);
    // gates = [h_tmp_i | xs | h] @ [Wih_i ; Whh_i] + lstm_b[i]  (M=4096,N=512,K=384)
    const float* Wih = lstm_Wih + (size_t)i * 256 * 512;
    const float* Whh = lstm_Whh + (size_t)i * 128 * 512;
    gemm64<<<dim3(8, NB / 64), 256, 0, stream>>>(
        htmp, xsbuf, hbuf,
        Wih, Wih + (size_t)128 * 512, Whh,
        lstm_b + (size_t)i * 512, gates, NB, 512, 384, 0);
    lstm_gate_kernel<<<(NB * H + 255) / 256, 256, 0, stream>>>(gates, cbuf, hbuf, xsbuf);
  }

  // lin2: l2out = xs @ lin2_W + lin2_b   (M=4096,N=128,K=128)
  gemm64<<<dim3(2, NB / 64), 256, 0, stream>>>(
      xsbuf, nullptr, nullptr, lin2_W, nullptr, nullptr, lin2_b, l2out, NB, H, 128, 0);

  scatter_out<<<(NB * H + 255) / 256, 256, 0, stream>>>(l2out, sel_map, root_idx, aggp, out);
}

// Round 2
// 539.904 us; speedup vs baseline: 1.4557x; 1.4557x over previous
//
#include <hip/hip_runtime.h>

// Problem constants (match reference)
constexpr int N  = 100000;   // nodes
constexpr int E  = 1600000;  // edges
constexpr int H  = 128;      // hidden
constexpr int NB = 4096;     // root pairs
constexpr int HOPS = 3;

// ---------------- workspace layout (byte offsets, 256B aligned) ---------------
constexpr size_t ALIGN = 256;
constexpr size_t alup(size_t x) { return (x + ALIGN - 1) & ~(ALIGN - 1); }

constexpr size_t OFF_X       = 0;                                        // [N,128] f32
constexpr size_t OFF_SSRC    = alup(OFF_X + (size_t)N * H * 4);          // [3][N] f32
constexpr size_t OFF_SDST    = alup(OFF_SSRC + (size_t)3 * N * 4);       // [3][N] f32
constexpr size_t OFF_WVEC    = alup(OFF_SDST + (size_t)3 * N * 4);       // [6][128] f32
constexpr size_t OFF_SELMAP  = alup(OFF_WVEC + 6 * H * 4);               // [N] int
constexpr size_t OFF_NODELST = alup(OFF_SELMAP + (size_t)N * 4);         // [4096] int
constexpr size_t OFF_CNT     = alup(OFF_NODELST + NB * 4);               // [2] int
constexpr size_t OFF_DEG     = alup(OFF_CNT + 256);                      // [4096] int
constexpr size_t OFF_OFFS    = alup(OFF_DEG + NB * 4);                   // [4097] int
constexpr size_t OFF_CURSOR  = alup(OFF_OFFS + (NB + 1) * 4);            // [4096] int
constexpr size_t OFF_ESORT   = alup(OFF_CURSOR + NB * 4);                // [E] int
constexpr size_t OFF_AGGX    = alup(OFF_ESORT + (size_t)E * 4);          // [3][4096][128] f32
constexpr size_t OFF_HTMP    = alup(OFF_AGGX + (size_t)3 * NB * H * 4);  // [4096][128]
constexpr size_t OFF_XS      = alup(OFF_HTMP + (size_t)NB * H * 4);      // [4096][128]
constexpr size_t OFF_HBUF    = alup(OFF_XS + (size_t)NB * H * 4);        // [4096][128]
constexpr size_t OFF_CBUF    = alup(OFF_HBUF + (size_t)NB * H * 4);      // [4096][128]
constexpr size_t OFF_GATES   = alup(OFF_CBUF + (size_t)NB * H * 4);      // [4096][512]
constexpr size_t OFF_L2OUT   = alup(OFF_GATES + (size_t)NB * 512 * 4);   // [4096][128]

__device__ __forceinline__ float lrelu(float v) { return v > 0.f ? v : 0.2f * v; }
__device__ __forceinline__ float sigmoidf_(float v) { return 1.f / (1.f + __expf(-v)); }

// ---------------- tiny setup kernels -----------------------------------------

__global__ void wvec_kernel(const float* __restrict__ gat_W,
                            const float* __restrict__ a_src,
                            const float* __restrict__ a_dst,
                            float* __restrict__ wvec) {
  int i = blockIdx.x >> 1, which = blockIdx.x & 1;
  int k = threadIdx.x;
  __shared__ float av[H];
  av[k] = which ? a_dst[i * H + k] : a_src[i * H + k];
  __syncthreads();
  const float* Wr = gat_W + (size_t)i * H * H + (size_t)k * H;
  float s = 0.f;
  #pragma unroll 8
  for (int j = 0; j < H; j++) s = fmaf(Wr[j], av[j], s);
  wvec[(i * 2 + which) * H + k] = s;
}

__global__ void mark_roots(const int* __restrict__ root, const int* __restrict__ aggp,
                           int* __restrict__ sel_map) {
  int b = blockIdx.x * 256 + threadIdx.x;
  if (b >= NB) return;
  int node = root[2 * b + (aggp[0] ? 0 : 1)];
  sel_map[node] = -2;   // all writers write the same value: benign race
}

__global__ void assign_ids(int* __restrict__ sel_map, int* __restrict__ node_list,
                           int* __restrict__ cnt) {
  int n = blockIdx.x * 256 + threadIdx.x;
  if (n >= N) return;
  if (sel_map[n] == -2) {
    int c = atomicAdd(cnt, 1);   // LLVM wave-aggregates; ~4096 total hits
    sel_map[n] = c;
    node_list[c] = n;
  }
}

// ---------------- GEMM: 128x128 tile, 8x8 microtile (for lin1) ----------------
__global__ __launch_bounds__(256)
void gemm128(const float* __restrict__ a0, const float* __restrict__ a1,
             const float* __restrict__ b0, const float* __restrict__ b1,
             const float* __restrict__ bias, float* __restrict__ Cc,
             int M, int Nn, int K) {
  __shared__ float As[16][132];
  __shared__ float Bs[16][128];
  const int t = threadIdx.x;
  const int row0 = blockIdx.y * 128;
  const int col0 = blockIdx.x * 128;
  const int tx = t & 15, ty = t >> 4;
  float acc[8][8];
  #pragma unroll
  for (int i = 0; i < 8; i++)
    #pragma unroll
    for (int j = 0; j < 8; j++) acc[i][j] = 0.f;

  const float* asegs[2] = {a0, a1};
  const float* bsegs[2] = {b0, b1};

  for (int k0 = 0; k0 < K; k0 += 16) {
    const float* abase = asegs[k0 >> 7] + (k0 & 127);
    const float* bbase = bsegs[k0 >> 7] + (size_t)(k0 & 127) * Nn + col0;
    #pragma unroll
    for (int l = 0; l < 2; l++) {
      int q = t + l * 256;
      int r = q >> 2;
      int kq = (q & 3) * 4;
      int gr = row0 + r;
      float4 v = make_float4(0.f, 0.f, 0.f, 0.f);
      if (gr < M) v = *(const float4*)(abase + (size_t)gr * H + kq);
      As[kq + 0][r] = v.x; As[kq + 1][r] = v.y; As[kq + 2][r] = v.z; As[kq + 3][r] = v.w;
    }
    #pragma unroll
    for (int l = 0; l < 2; l++) {
      int q = t + l * 256;
      int kk = q >> 5;
      int c = (q & 31) * 4;
      *(float4*)(&Bs[kk][c]) = *(const float4*)(bbase + (size_t)kk * Nn + c);
    }
    __syncthreads();
    #pragma unroll
    for (int kk = 0; kk < 16; kk++) {
      float ar[8], br[8];
      *(float4*)&ar[0] = *(const float4*)&As[kk][ty * 8];
      *(float4*)&ar[4] = *(const float4*)&As[kk][ty * 8 + 4];
      *(float4*)&br[0] = *(const float4*)&Bs[kk][tx * 8];
      *(float4*)&br[4] = *(const float4*)&Bs[kk][tx * 8 + 4];
      #pragma unroll
      for (int i = 0; i < 8; i++)
        #pragma unroll
        for (int j = 0; j < 8; j++) acc[i][j] = fmaf(ar[i], br[j], acc[i][j]);
    }
    __syncthreads();
  }
  #pragma unroll
  for (int i = 0; i < 8; i++) {
    int r = row0 + ty * 8 + i;
    if (r < M) {
      int cb = col0 + tx * 8;
      float* crow = Cc + (size_t)r * Nn + cb;
      float4 v0, v1;
      v0.x = acc[i][0] + bias[cb + 0]; v0.y = acc[i][1] + bias[cb + 1];
      v0.z = acc[i][2] + bias[cb + 2]; v0.w = acc[i][3] + bias[cb + 3];
      v1.x = acc[i][4] + bias[cb + 4]; v1.y = acc[i][5] + bias[cb + 5];
      v1.z = acc[i][6] + bias[cb + 6]; v1.w = acc[i][7] + bias[cb + 7];
      *(float4*)crow = v0;
      *(float4*)(crow + 4) = v1;
    }
  }
}

// ---------------- GEMM: 64x64 tile, 4x4 microtile (small GEMMs) ---------------
__global__ __launch_bounds__(256)
void gemm64(const float* __restrict__ a0, const float* __restrict__ a1,
            const float* __restrict__ a2,
            const float* __restrict__ b0, const float* __restrict__ b1,
            const float* __restrict__ b2,
            const float* __restrict__ bias, float* __restrict__ Cc,
            int M, int Nn, int K, int act) {
  __shared__ float As[16][68];
  __shared__ float Bs[16][64];
  const int t = threadIdx.x;
  const int row0 = blockIdx.y * 64;
  const int col0 = blockIdx.x * 64;
  const int tx = t & 15, ty = t >> 4;
  float acc[4][4];
  #pragma unroll
  for (int i = 0; i < 4; i++)
    #pragma unroll
    for (int j = 0; j < 4; j++) acc[i][j] = 0.f;

  const float* asegs[3] = {a0, a1, a2};
  const float* bsegs[3] = {b0, b1, b2};

  for (int k0 = 0; k0 < K; k0 += 16) {
    const float* abase = asegs[k0 >> 7] + (k0 & 127);
    const float* bbase = bsegs[k0 >> 7] + (size_t)(k0 & 127) * Nn + col0;
    {
      int r = t >> 2, kq = (t & 3) * 4;
      int gr = row0 + r;
      float4 v = make_float4(0.f, 0.f, 0.f, 0.f);
      if (gr < M) v = *(const float4*)(abase + (size_t)gr * H + kq);
      As[kq + 0][r] = v.x; As[kq + 1][r] = v.y; As[kq + 2][r] = v.z; As[kq + 3][r] = v.w;
      int kk = t >> 4, c = (t & 15) * 4;
      *(float4*)(&Bs[kk][c]) = *(const float4*)(bbase + (size_t)kk * Nn + c);
    }
    __syncthreads();
    #pragma unroll
    for (int kk = 0; kk < 16; kk++) {
      float4 a4 = *(const float4*)&As[kk][ty * 4];
      float4 b4 = *(const float4*)&Bs[kk][tx * 4];
      float ar[4] = {a4.x, a4.y, a4.z, a4.w};
      float br[4] = {b4.x, b4.y, b4.z, b4.w};
      #pragma unroll
      for (int i = 0; i < 4; i++)
        #pragma unroll
        for (int j = 0; j < 4; j++) acc[i][j] = fmaf(ar[i], br[j], acc[i][j]);
    }
    __syncthreads();
  }
  #pragma unroll
  for (int i = 0; i < 4; i++) {
    int r = row0 + ty * 4 + i;
    if (r < M) {
      int cb = col0 + tx * 4;
      float4 v;
      v.x = acc[i][0] + bias[cb + 0];
      v.y = acc[i][1] + bias[cb + 1];
      v.z = acc[i][2] + bias[cb + 2];
      v.w = acc[i][3] + bias[cb + 3];
      if (act == 1) { v.x = tanhf(v.x); v.y = tanhf(v.y); v.z = tanhf(v.z); v.w = tanhf(v.w); }
      *(float4*)(Cc + (size_t)r * Nn + cb) = v;
    }
  }
}

// ---------------- attention score vectors: s = x @ wvec ----------------------
__global__ __launch_bounds__(256)
void score_kernel(const float* __restrict__ x, const float* __restrict__ wvec,
                  float* __restrict__ s_src, float* __restrict__ s_dst) {
  int wv = blockIdx.x * 4 + (threadIdx.x >> 6);
  int lane = threadIdx.x & 63;
  if (wv >= N) return;
  float2 v = *(const float2*)(x + (size_t)wv * H + lane * 2);
  float acc[6];
  #pragma unroll
  for (int i = 0; i < 6; i++) {
    float2 w = *(const float2*)(wvec + i * H + lane * 2);
    acc[i] = v.x * w.x + v.y * w.y;
  }
  #pragma unroll
  for (int off = 32; off > 0; off >>= 1)
    #pragma unroll
    for (int i = 0; i < 6; i++) acc[i] += __shfl_down(acc[i], off);
  if (lane == 0) {
    #pragma unroll
    for (int i = 0; i < 3; i++) {
      s_src[i * N + wv] = acc[2 * i + 0];
      s_dst[i * N + wv] = acc[2 * i + 1];
    }
  }
}

// ---------------- edge CSR by destination: count + scan + scatter --------------
// No single-address atomic anywhere on the edge path (R1: 268us stall on ecnt).
__global__ void count_edges(const int* __restrict__ ei, const int* __restrict__ sel_map,
                            int* __restrict__ deg) {
  int e = blockIdx.x * 256 + threadIdx.x;
  if (e >= E) return;
  int d = sel_map[ei[E + e]];
  if (d >= 0) atomicAdd(&deg[d], 1);   // spread over 4096 addresses
}

__global__ __launch_bounds__(1024)
void scan_kernel(const int* __restrict__ deg, int* __restrict__ offs) {
  __shared__ int part[1024];
  int t = threadIdx.x;
  int base = t * 4;
  int v0 = deg[base], v1 = deg[base + 1], v2 = deg[base + 2], v3 = deg[base + 3];
  int s = v0 + v1 + v2 + v3;
  part[t] = s;
  __syncthreads();
  for (int off = 1; off < 1024; off <<= 1) {
    int tmp = (t >= off) ? part[t - off] : 0;
    __syncthreads();
    part[t] += tmp;
    __syncthreads();
  }
  int run = part[t] - s;
  offs[base] = run; run += v0;
  offs[base + 1] = run; run += v1;
  offs[base + 2] = run; run += v2;
  offs[base + 3] = run; run += v3;
  if (t == 1023) offs[NB] = part[1023];
}

__global__ void scatter_edges2(const int* __restrict__ ei, const int* __restrict__ sel_map,
                               const int* __restrict__ offs, int* __restrict__ cursor,
                               int* __restrict__ es_sorted) {
  int e = blockIdx.x * 256 + threadIdx.x;
  if (e >= E) return;
  int d = sel_map[ei[E + e]];
  if (d >= 0) {
    int p = atomicAdd(&cursor[d], 1);  // spread over 4096 addresses
    es_sorted[offs[d] + p] = ei[e];
  }
}

// ---------------- per-destination GAT softmax aggregation ---------------------
__global__ __launch_bounds__(128)
void gat_node_kernel(const int* __restrict__ node_list, const int* __restrict__ cntp,
                     const int* __restrict__ offs, const int* __restrict__ es_sorted,
                     const float* __restrict__ x, const float* __restrict__ s_src,
                     const float* __restrict__ s_dst,
                     float* __restrict__ aggx, float* __restrict__ xsbuf) {
  int c = blockIdx.x;
  if (c >= cntp[0]) return;
  int t = threadIdx.x;
  int n = node_list[c];
  float xv = x[(size_t)n * H + t];
  xsbuf[(size_t)c * H + t] = xv;
  float sd0 = s_dst[0 * N + n], sd1 = s_dst[1 * N + n], sd2 = s_dst[2 * N + n];
  int e0 = offs[c], e1 = offs[c + 1];
  float m0 = -1e30f, m1 = -1e30f, m2 = -1e30f;
  for (int e = e0 + t; e < e1; e += 128) {
    int s = es_sorted[e];
    m0 = fmaxf(m0, lrelu(s_src[0 * N + s] + sd0));
    m1 = fmaxf(m1, lrelu(s_src[1 * N + s] + sd1));
    m2 = fmaxf(m2, lrelu(s_src[2 * N + s] + sd2));
  }
  __shared__ float red[3][128];
  red[0][t] = m0; red[1][t] = m1; red[2][t] = m2;
  __syncthreads();
  for (int s2 = 64; s2 > 0; s2 >>= 1) {
    if (t < s2) {
      red[0][t] = fmaxf(red[0][t], red[0][t + s2]);
      red[1][t] = fmaxf(red[1][t], red[1][t + s2]);
      red[2][t] = fmaxf(red[2][t], red[2][t + s2]);
    }
    __syncthreads();
  }
  m0 = red[0][0]; m1 = red[1][0]; m2 = red[2][0];
  float u0 = 0.f, u1 = 0.f, u2 = 0.f, z0 = 0.f, z1 = 0.f, z2 = 0.f;
  for (int e = e0; e < e1; e++) {
    int s = es_sorted[e];
    float xs = x[(size_t)s * H + t];
    float ex0 = __expf(lrelu(s_src[0 * N + s] + sd0) - m0);
    float ex1 = __expf(lrelu(s_src[1 * N + s] + sd1) - m1);
    float ex2 = __expf(lrelu(s_src[2 * N + s] + sd2) - m2);
    z0 += ex0; z1 += ex1; z2 += ex2;
    u0 = fmaf(ex0, xs, u0); u1 = fmaf(ex1, xs, u1); u2 = fmaf(ex2, xs, u2);
  }
  size_t cb = (size_t)c * H + t;
  bool any = e1 > e0;
  aggx[0 * ((size_t)NB * H) + cb] = any ? u0 / z0 : 0.f;
  aggx[1 * ((size_t)NB * H) + cb] = any ? u1 / z1 : 0.f;
  aggx[2 * ((size_t)NB * H) + cb] = any ? u2 / z2 : 0.f;
}

// ---------------- LSTM gate nonlinearity --------------------------------------
__global__ void lstm_gate_kernel(const float* __restrict__ gates,
                                 float* __restrict__ cbuf, float* __restrict__ hbuf,
                                 float* __restrict__ xsbuf) {
  int id = blockIdx.x * 256 + threadIdx.x;
  if (id >= NB * H) return;
  int c = id >> 7, j = id & 127;
  const float* g = gates + (size_t)c * 512;
  float gi = g[j], gf = g[128 + j], gg = g[256 + j], go = g[384 + j];
  float cp = cbuf[id];
  float cn = sigmoidf_(gf) * cp + sigmoidf_(gi) * tanhf(gg);
  float hn = sigmoidf_(go) * tanhf(cn);
  cbuf[id] = cn;
  hbuf[id] = hn;
  xsbuf[id] = hn;
}

// ---------------- output gather ------------------------------------------------
__global__ void scatter_out(const float* __restrict__ l2out, const int* __restrict__ sel_map,
                            const int* __restrict__ root, const int* __restrict__ aggp,
                            float* __restrict__ out) {
  int id = blockIdx.x * 256 + threadIdx.x;
  if (id >= NB * H) return;
  int b = id >> 7, f = id & 127;
  int node = root[2 * b + (aggp[0] ? 0 : 1)];
  int c = sel_map[node];
  out[id] = l2out[(size_t)c * H + f];
}

// ==============================================================================
extern "C" void kernel_launch(void* const* d_in, const int* in_sizes, int n_in,
                              void* d_out, int out_size, void* d_ws, size_t ws_size,
                              hipStream_t stream) {
  const float* node_feat = (const float*)d_in[0];
  const float* send_embd = (const float*)d_in[1];
  const int*   edge_idx  = (const int*)d_in[2];
  const int*   root_idx  = (const int*)d_in[3];
  const int*   aggp      = (const int*)d_in[4];
  const float* lin1_W    = (const float*)d_in[5];
  const float* lin1_b    = (const float*)d_in[6];
  const float* gat_W     = (const float*)d_in[7];
  const float* gat_asrc  = (const float*)d_in[8];
  const float* gat_adst  = (const float*)d_in[9];
  const float* gat_b     = (const float*)d_in[10];
  const float* lstm_Wih  = (const float*)d_in[11];
  const float* lstm_Whh  = (const float*)d_in[12];
  const float* lstm_b    = (const float*)d_in[13];
  const float* lin2_W    = (const float*)d_in[14];
  const float* lin2_b    = (const float*)d_in[15];
  float* out = (float*)d_out;

  char* ws = (char*)d_ws;
  float* x       = (float*)(ws + OFF_X);
  float* s_src   = (float*)(ws + OFF_SSRC);
  float* s_dst   = (float*)(ws + OFF_SDST);
  float* wvec    = (float*)(ws + OFF_WVEC);
  int*   sel_map = (int*)(ws + OFF_SELMAP);
  int*   nodelst = (int*)(ws + OFF_NODELST);
  int*   cnt     = (int*)(ws + OFF_CNT);
  int*   deg     = (int*)(ws + OFF_DEG);
  int*   offs    = (int*)(ws + OFF_OFFS);
  int*   cursor  = (int*)(ws + OFF_CURSOR);
  int*   esort   = (int*)(ws + OFF_ESORT);
  float* aggx    = (float*)(ws + OFF_AGGX);
  float* htmp    = (float*)(ws + OFF_HTMP);
  float* xsbuf   = (float*)(ws + OFF_XS);
  float* hbuf    = (float*)(ws + OFF_HBUF);
  float* cbuf    = (float*)(ws + OFF_CBUF);
  float* gates   = (float*)(ws + OFF_GATES);
  float* l2out   = (float*)(ws + OFF_L2OUT);

  hipMemsetAsync(sel_map, 0xFF, (size_t)N * 4, stream);   // -1
  hipMemsetAsync(cnt, 0, 256, stream);
  hipMemsetAsync(deg, 0, NB * 4, stream);
  hipMemsetAsync(cursor, 0, NB * 4, stream);
  hipMemsetAsync(hbuf, 0, (size_t)NB * H * 4, stream);
  hipMemsetAsync(cbuf, 0, (size_t)NB * H * 4, stream);

  wvec_kernel<<<6, 128, 0, stream>>>(gat_W, gat_asrc, gat_adst, wvec);
  mark_roots<<<(NB + 255) / 256, 256, 0, stream>>>(root_idx, aggp, sel_map);
  assign_ids<<<(N + 255) / 256, 256, 0, stream>>>(sel_map, nodelst, cnt);

  // lin1: x = [node_feat | send_embd] @ lin1_W + lin1_b   (M=N, N=128, K=256)
  gemm128<<<dim3(1, (N + 127) / 128), 256, 0, stream>>>(
      node_feat, send_embd, lin1_W, lin1_W + 128 * H, lin1_b, x, N, H, 256);

  score_kernel<<<(N + 3) / 4, 256, 0, stream>>>(x, wvec, s_src, s_dst);

  count_edges<<<(E + 255) / 256, 256, 0, stream>>>(edge_idx, sel_map, deg);
  scan_kernel<<<1, 1024, 0, stream>>>(deg, offs);
  scatter_edges2<<<(E + 255) / 256, 256, 0, stream>>>(edge_idx, sel_map, offs, cursor, esort);
  gat_node_kernel<<<NB, 128, 0, stream>>>(nodelst, cnt, offs, esort, x, s_src, s_dst,
                                          aggx, xsbuf);

  for (int i = 0; i < HOPS; i++) {
    gemm64<<<dim3(2, NB / 64), 256, 0, stream>>>(
        aggx + (size_t)i * NB * H, nullptr, nullptr,
        gat_W + (size_t)i * H * H, nullptr, nullptr,
        gat_b + (size_t)i * H, htmp, NB, H, 128, 1);
    const float* Wih = lstm_Wih + (size_t)i * 256 * 512;
    const float* Whh = lstm_Whh + (size_t)i * 128 * 512;
    gemm64<<<dim3(8, NB / 64), 256, 0, stream>>>(
        htmp, xsbuf, hbuf,
        Wih, Wih + (size_t)128 * 512, Whh,
        lstm_b + (size_t)i * 512, gates, NB, 512, 384, 0);
    lstm_gate_kernel<<<(NB * H + 255) / 256, 256, 0, stream>>>(gates, cbuf, hbuf, xsbuf);
  }

  gemm64<<<dim3(2, NB / 64), 256, 0, stream>>>(
      xsbuf, nullptr, nullptr, lin2_W, nullptr, nullptr, lin2_b, l2out, NB, H, 128, 0);

  scatter_out<<<(NB * H + 255) / 256, 256, 0, stream>>>(l2out, sel_map, root_idx, aggp, out);
}

// Round 3
// 484.175 us; speedup vs baseline: 1.6232x; 1.1151x over previous
//
#include <hip/hip_runtime.h>

// Problem constants (match reference)
constexpr int N  = 100000;   // nodes
constexpr int E  = 1600000;  // edges
constexpr int H  = 128;      // hidden
constexpr int NB = 4096;     // root pairs
constexpr int HOPS = 3;

// Converted-weight buffer layout (element offsets into whi/wlo ushort arrays)
constexpr int WOFF_L1  = 0;                      // [256][128] lin1_W
constexpr int WOFF_GAT = 32768;                  // 3 x [128][128] gat_W
constexpr int WOFF_CAT = 81920;                  // 3 x [384][512] [Wih;Whh]
constexpr int WOFF_L2  = 671744;                 // [128][128] lin2_W
constexpr int WTOT     = 688128;

// ---------------- workspace layout (byte offsets, 256B aligned) ---------------
constexpr size_t ALIGN = 256;
constexpr size_t alup(size_t x) { return (x + ALIGN - 1) & ~(ALIGN - 1); }

constexpr size_t OFF_X       = 0;                                        // [N,128] f32
constexpr size_t OFF_SSRC    = alup(OFF_X + (size_t)N * H * 4);          // [3][N] f32
constexpr size_t OFF_SDST    = alup(OFF_SSRC + (size_t)3 * N * 4);       // [3][N] f32
constexpr size_t OFF_WVEC    = alup(OFF_SDST + (size_t)3 * N * 4);       // [6][128] f32
constexpr size_t OFF_SELMAP  = alup(OFF_WVEC + 6 * H * 4);               // [N] int
constexpr size_t OFF_NODELST = alup(OFF_SELMAP + (size_t)N * 4);         // [4096] int
constexpr size_t OFF_CNT     = alup(OFF_NODELST + NB * 4);               // [2] int
constexpr size_t OFF_DEG     = alup(OFF_CNT + 256);                      // [4096] int
constexpr size_t OFF_OFFS    = alup(OFF_DEG + NB * 4);                   // [4097] int
constexpr size_t OFF_CURSOR  = alup(OFF_OFFS + (NB + 1) * 4);            // [4096] int
constexpr size_t OFF_ESORT   = alup(OFF_CURSOR + NB * 4);                // [E] int
constexpr size_t OFF_AGGX    = alup(OFF_ESORT + (size_t)E * 4);          // [3][4096][128] f32
constexpr size_t OFF_HTMP    = alup(OFF_AGGX + (size_t)3 * NB * H * 4);  // [4096][128]
constexpr size_t OFF_XS      = alup(OFF_HTMP + (size_t)NB * H * 4);      // [4096][128]
constexpr size_t OFF_HBUF    = alup(OFF_XS + (size_t)NB * H * 4);        // [4096][128]
constexpr size_t OFF_CBUF    = alup(OFF_HBUF + (size_t)NB * H * 4);      // [4096][128]
constexpr size_t OFF_GATES   = alup(OFF_CBUF + (size_t)NB * H * 4);      // [4096][512]
constexpr size_t OFF_L2OUT   = alup(OFF_GATES + (size_t)NB * 512 * 4);   // [4096][128]
constexpr size_t OFF_WHI     = alup(OFF_L2OUT + (size_t)NB * H * 4);     // [WTOT] ushort
constexpr size_t OFF_WLO     = alup(OFF_WHI + (size_t)WTOT * 2);         // [WTOT] ushort

__device__ __forceinline__ float lrelu(float v) { return v > 0.f ? v : 0.2f * v; }
__device__ __forceinline__ float sigmoidf_(float v) { return 1.f / (1.f + __expf(-v)); }

__device__ __forceinline__ unsigned short f2bf(float f) {
  unsigned u = __float_as_uint(f);
  unsigned r = (u + 0x7FFFu + ((u >> 16) & 1u)) >> 16;
  return (unsigned short)r;
}
__device__ __forceinline__ float bf2f(unsigned short h) {
  return __uint_as_float((unsigned)h << 16);
}

typedef short bf16x8 __attribute__((ext_vector_type(8)));
typedef float f32x4  __attribute__((ext_vector_type(4)));

// ---------------- tiny setup kernels -----------------------------------------

__global__ void wvec_kernel(const float* __restrict__ gat_W,
                            const float* __restrict__ a_src,
                            const float* __restrict__ a_dst,
                            float* __restrict__ wvec) {
  int i = blockIdx.x >> 1, which = blockIdx.x & 1;
  int k = threadIdx.x;
  __shared__ float av[H];
  av[k] = which ? a_dst[i * H + k] : a_src[i * H + k];
  __syncthreads();
  const float* Wr = gat_W + (size_t)i * H * H + (size_t)k * H;
  float s = 0.f;
  #pragma unroll 8
  for (int j = 0; j < H; j++) s = fmaf(Wr[j], av[j], s);
  wvec[(i * 2 + which) * H + k] = s;
}

__global__ void mark_roots(const int* __restrict__ root, const int* __restrict__ aggp,
                           int* __restrict__ sel_map) {
  int b = blockIdx.x * 256 + threadIdx.x;
  if (b >= NB) return;
  int node = root[2 * b + (aggp[0] ? 0 : 1)];
  sel_map[node] = -2;   // all writers write the same value: benign race
}

__global__ void assign_ids(int* __restrict__ sel_map, int* __restrict__ node_list,
                           int* __restrict__ cnt) {
  int n = blockIdx.x * 256 + threadIdx.x;
  if (n >= N) return;
  if (sel_map[n] == -2) {
    int c = atomicAdd(cnt, 1);   // LLVM wave-aggregates
    sel_map[n] = c;
    node_list[c] = n;
  }
}

// ---------------- weight conversion fp32 -> bf16 hi/lo ------------------------
__global__ void convert_weights(const float* __restrict__ lin1_W,
                                const float* __restrict__ gat_W,
                                const float* __restrict__ Wih,
                                const float* __restrict__ Whh,
                                const float* __restrict__ lin2_W,
                                unsigned short* __restrict__ whi,
                                unsigned short* __restrict__ wlo) {
  int idx = blockIdx.x * 256 + threadIdx.x;
  if (idx >= WTOT) return;
  float v;
  if (idx < WOFF_GAT) {
    v = lin1_W[idx];
  } else if (idx < WOFF_CAT) {
    v = gat_W[idx - WOFF_GAT];
  } else if (idx < WOFF_L2) {
    int r = idx - WOFF_CAT;
    int hop = r / 196608, q = r % 196608;
    v = (q < 131072) ? Wih[hop * 131072 + q] : Whh[hop * 65536 + (q - 131072)];
  } else {
    v = lin2_W[idx - WOFF_L2];
  }
  unsigned short hh = f2bf(v);
  whi[idx] = hh;
  wlo[idx] = f2bf(v - bf2f(hh));
}

// ---------------- unified split-bf16 MFMA GEMM --------------------------------
// C[M][Nn] = concat_k(asegs fp32 [M][128]) @ B[K][Nn] + bias;  K = 128*nseg.
// B pre-converted to bf16 hi/lo (ushort). 3-product split: hi*hi + hi*lo + lo*hi.
// Block: 256 thr = 4 waves; block tile 256 rows x 64 cols; wave = 64 rows.
// Layouts (verified, m89/m91/m120): A[m=lane&15][k=quad*8+j];
// B[k=quad*8+j][n=lane&15] (LDS stored [n][k], pitch 136 -> 2-way = free);
// D row = quad*4+reg, col = lane&15.
__global__ __launch_bounds__(256)
void gemm_mfma(const float* __restrict__ a0, const float* __restrict__ a1,
               const float* __restrict__ a2,
               const unsigned short* __restrict__ Bhi,
               const unsigned short* __restrict__ Blo,
               const float* __restrict__ bias, float* __restrict__ Cc,
               int M, int Nn, int nseg, int act) {
  __shared__ unsigned short Bs[2][64 * 136];
  const int t = threadIdx.x;
  const int lane = t & 63, wave = t >> 6;
  const int nl = lane & 15, quad = lane >> 4;
  const int n0 = blockIdx.x * 64;
  const int rt = blockIdx.y * 256 + wave * 64;
  const float* asegs[3] = {a0, a1, a2};

  f32x4 acc[4][4];
  #pragma unroll
  for (int i = 0; i < 4; i++)
    #pragma unroll
    for (int j = 0; j < 4; j++) acc[i][j] = (f32x4){0.f, 0.f, 0.f, 0.f};

  for (int ks = 0; ks < nseg; ks++) {
    // stage B slab (128 k x 64 n) into LDS transposed [n][k]
    {
      int nld = t & 63, kb = t >> 6;
      const unsigned short* gh = Bhi + (size_t)ks * 128 * Nn + n0 + nld;
      const unsigned short* gl = Blo + (size_t)ks * 128 * Nn + n0 + nld;
      #pragma unroll 4
      for (int j = 0; j < 32; j++) {
        int k = kb + j * 4;
        Bs[0][nld * 136 + k] = gh[(size_t)k * Nn];
        Bs[1][nld * 136 + k] = gl[(size_t)k * Nn];
      }
    }
    __syncthreads();
    const float* A = asegs[ks];
    #pragma unroll
    for (int kt = 0; kt < 4; kt++) {
      bf16x8 ahi[4], alo[4];
      #pragma unroll
      for (int i = 0; i < 4; i++) {
        int row = rt + i * 16 + nl;
        const float* p = A + (size_t)row * H + kt * 32 + quad * 8;
        float4 v0 = make_float4(0.f, 0.f, 0.f, 0.f), v1 = v0;
        if (row < M) { v0 = *(const float4*)p; v1 = *(const float4*)(p + 4); }
        float af[8] = {v0.x, v0.y, v0.z, v0.w, v1.x, v1.y, v1.z, v1.w};
        #pragma unroll
        for (int j = 0; j < 8; j++) {
          unsigned short hh = f2bf(af[j]);
          ahi[i][j] = (short)hh;
          alo[i][j] = (short)f2bf(af[j] - bf2f(hh));
        }
      }
      bf16x8 bhi[4], blo[4];
      #pragma unroll
      for (int j = 0; j < 4; j++) {
        int off = (j * 16 + nl) * 136 + kt * 32 + quad * 8;
        bhi[j] = *(const bf16x8*)&Bs[0][off];
        blo[j] = *(const bf16x8*)&Bs[1][off];
      }
      #pragma unroll
      for (int i = 0; i < 4; i++)
        #pragma unroll
        for (int j = 0; j < 4; j++) {
          acc[i][j] = __builtin_amdgcn_mfma_f32_16x16x32_bf16(ahi[i], bhi[j], acc[i][j], 0, 0, 0);
          acc[i][j] = __builtin_amdgcn_mfma_f32_16x16x32_bf16(ahi[i], blo[j], acc[i][j], 0, 0, 0);
          acc[i][j] = __builtin_amdgcn_mfma_f32_16x16x32_bf16(alo[i], bhi[j], acc[i][j], 0, 0, 0);
        }
    }
    __syncthreads();
  }

  // epilogue: bias (+ optional tanh), store
  float bv[4];
  #pragma unroll
  for (int j = 0; j < 4; j++) bv[j] = bias[n0 + j * 16 + nl];
  #pragma unroll
  for (int i = 0; i < 4; i++) {
    #pragma unroll
    for (int r = 0; r < 4; r++) {
      int rr = rt + i * 16 + quad * 4 + r;
      if (rr < M) {
        float* cr = Cc + (size_t)rr * Nn + n0 + nl;
        #pragma unroll
        for (int j = 0; j < 4; j++) {
          float v = acc[i][j][r] + bv[j];
          if (act) v = tanhf(v);
          cr[j * 16] = v;
        }
      }
    }
  }
}

// ---------------- attention score vectors: s = x @ wvec ----------------------
__global__ __launch_bounds__(256)
void score_kernel(const float* __restrict__ x, const float* __restrict__ wvec,
                  float* __restrict__ s_src, float* __restrict__ s_dst) {
  int wv = blockIdx.x * 4 + (threadIdx.x >> 6);
  int lane = threadIdx.x & 63;
  if (wv >= N) return;
  float2 v = *(const float2*)(x + (size_t)wv * H + lane * 2);
  float acc[6];
  #pragma unroll
  for (int i = 0; i < 6; i++) {
    float2 w = *(const float2*)(wvec + i * H + lane * 2);
    acc[i] = v.x * w.x + v.y * w.y;
  }
  #pragma unroll
  for (int off = 32; off > 0; off >>= 1)
    #pragma unroll
    for (int i = 0; i < 6; i++) acc[i] += __shfl_down(acc[i], off);
  if (lane == 0) {
    #pragma unroll
    for (int i = 0; i < 3; i++) {
      s_src[i * N + wv] = acc[2 * i + 0];
      s_dst[i * N + wv] = acc[2 * i + 1];
    }
  }
}

// ---------------- edge CSR by destination: count + scan + scatter --------------
__global__ void count_edges(const int* __restrict__ ei, const int* __restrict__ sel_map,
                            int* __restrict__ deg) {
  int e = blockIdx.x * 256 + threadIdx.x;
  if (e >= E) return;
  int d = sel_map[ei[E + e]];
  if (d >= 0) atomicAdd(&deg[d], 1);
}

__global__ __launch_bounds__(1024)
void scan_kernel(const int* __restrict__ deg, int* __restrict__ offs) {
  __shared__ int part[1024];
  int t = threadIdx.x;
  int base = t * 4;
  int v0 = deg[base], v1 = deg[base + 1], v2 = deg[base + 2], v3 = deg[base + 3];
  int s = v0 + v1 + v2 + v3;
  part[t] = s;
  __syncthreads();
  for (int off = 1; off < 1024; off <<= 1) {
    int tmp = (t >= off) ? part[t - off] : 0;
    __syncthreads();
    part[t] += tmp;
    __syncthreads();
  }
  int run = part[t] - s;
  offs[base] = run; run += v0;
  offs[base + 1] = run; run += v1;
  offs[base + 2] = run; run += v2;
  offs[base + 3] = run; run += v3;
  if (t == 1023) offs[NB] = part[1023];
}

__global__ void scatter_edges2(const int* __restrict__ ei, const int* __restrict__ sel_map,
                               const int* __restrict__ offs, int* __restrict__ cursor,
                               int* __restrict__ es_sorted) {
  int e = blockIdx.x * 256 + threadIdx.x;
  if (e >= E) return;
  int d = sel_map[ei[E + e]];
  if (d >= 0) {
    int p = atomicAdd(&cursor[d], 1);
    es_sorted[offs[d] + p] = ei[e];
  }
}

// ---------------- per-destination GAT softmax aggregation ---------------------
__global__ __launch_bounds__(128)
void gat_node_kernel(const int* __restrict__ node_list, const int* __restrict__ cntp,
                     const int* __restrict__ offs, const int* __restrict__ es_sorted,
                     const float* __restrict__ x, const float* __restrict__ s_src,
                     const float* __restrict__ s_dst,
                     float* __restrict__ aggx, float* __restrict__ xsbuf) {
  int c = blockIdx.x;
  if (c >= cntp[0]) return;
  int t = threadIdx.x;
  int n = node_list[c];
  float xv = x[(size_t)n * H + t];
  xsbuf[(size_t)c * H + t] = xv;
  float sd0 = s_dst[0 * N + n], sd1 = s_dst[1 * N + n], sd2 = s_dst[2 * N + n];
  int e0 = offs[c], e1 = offs[c + 1];
  float m0 = -1e30f, m1 = -1e30f, m2 = -1e30f;
  for (int e = e0 + t; e < e1; e += 128) {
    int s = es_sorted[e];
    m0 = fmaxf(m0, lrelu(s_src[0 * N + s] + sd0));
    m1 = fmaxf(m1, lrelu(s_src[1 * N + s] + sd1));
    m2 = fmaxf(m2, lrelu(s_src[2 * N + s] + sd2));
  }
  __shared__ float red[3][128];
  red[0][t] = m0; red[1][t] = m1; red[2][t] = m2;
  __syncthreads();
  for (int s2 = 64; s2 > 0; s2 >>= 1) {
    if (t < s2) {
      red[0][t] = fmaxf(red[0][t], red[0][t + s2]);
      red[1][t] = fmaxf(red[1][t], red[1][t + s2]);
      red[2][t] = fmaxf(red[2][t], red[2][t + s2]);
    }
    __syncthreads();
  }
  m0 = red[0][0]; m1 = red[1][0]; m2 = red[2][0];
  float u0 = 0.f, u1 = 0.f, u2 = 0.f, z0 = 0.f, z1 = 0.f, z2 = 0.f;
  for (int e = e0; e < e1; e++) {
    int s = es_sorted[e];
    float xs = x[(size_t)s * H + t];
    float ex0 = __expf(lrelu(s_src[0 * N + s] + sd0) - m0);
    float ex1 = __expf(lrelu(s_src[1 * N + s] + sd1) - m1);
    float ex2 = __expf(lrelu(s_src[2 * N + s] + sd2) - m2);
    z0 += ex0; z1 += ex1; z2 += ex2;
    u0 = fmaf(ex0, xs, u0); u1 = fmaf(ex1, xs, u1); u2 = fmaf(ex2, xs, u2);
  }
  size_t cb = (size_t)c * H + t;
  bool any = e1 > e0;
  aggx[0 * ((size_t)NB * H) + cb] = any ? u0 / z0 : 0.f;
  aggx[1 * ((size_t)NB * H) + cb] = any ? u1 / z1 : 0.f;
  aggx[2 * ((size_t)NB * H) + cb] = any ? u2 / z2 : 0.f;
}

// ---------------- LSTM gate nonlinearity --------------------------------------
__global__ void lstm_gate_kernel(const float* __restrict__ gates,
                                 float* __restrict__ cbuf, float* __restrict__ hbuf,
                                 float* __restrict__ xsbuf) {
  int id = blockIdx.x * 256 + threadIdx.x;
  if (id >= NB * H) return;
  int c = id >> 7, j = id & 127;
  const float* g = gates + (size_t)c * 512;
  float gi = g[j], gf = g[128 + j], gg = g[256 + j], go = g[384 + j];
  float cp = cbuf[id];
  float cn = sigmoidf_(gf) * cp + sigmoidf_(gi) * tanhf(gg);
  float hn = sigmoidf_(go) * tanhf(cn);
  cbuf[id] = cn;
  hbuf[id] = hn;
  xsbuf[id] = hn;
}

// ---------------- output gather ------------------------------------------------
__global__ void scatter_out(const float* __restrict__ l2out, const int* __restrict__ sel_map,
                            const int* __restrict__ root, const int* __restrict__ aggp,
                            float* __restrict__ out) {
  int id = blockIdx.x * 256 + threadIdx.x;
  if (id >= NB * H) return;
  int b = id >> 7, f = id & 127;
  int node = root[2 * b + (aggp[0] ? 0 : 1)];
  int c = sel_map[node];
  out[id] = l2out[(size_t)c * H + f];
}

// ==============================================================================
extern "C" void kernel_launch(void* const* d_in, const int* in_sizes, int n_in,
                              void* d_out, int out_size, void* d_ws, size_t ws_size,
                              hipStream_t stream) {
  const float* node_feat = (const float*)d_in[0];
  const float* send_embd = (const float*)d_in[1];
  const int*   edge_idx  = (const int*)d_in[2];
  const int*   root_idx  = (const int*)d_in[3];
  const int*   aggp      = (const int*)d_in[4];
  const float* lin1_W    = (const float*)d_in[5];
  const float* lin1_b    = (const float*)d_in[6];
  const float* gat_W     = (const float*)d_in[7];
  const float* gat_asrc  = (const float*)d_in[8];
  const float* gat_adst  = (const float*)d_in[9];
  const float* gat_b     = (const float*)d_in[10];
  const float* lstm_Wih  = (const float*)d_in[11];
  const float* lstm_Whh  = (const float*)d_in[12];
  const float* lstm_b    = (const float*)d_in[13];
  const float* lin2_W    = (const float*)d_in[14];
  const float* lin2_b    = (const float*)d_in[15];
  float* out = (float*)d_out;

  char* ws = (char*)d_ws;
  float* x       = (float*)(ws + OFF_X);
  float* s_src   = (float*)(ws + OFF_SSRC);
  float* s_dst   = (float*)(ws + OFF_SDST);
  float* wvec    = (float*)(ws + OFF_WVEC);
  int*   sel_map = (int*)(ws + OFF_SELMAP);
  int*   nodelst = (int*)(ws + OFF_NODELST);
  int*   cnt     = (int*)(ws + OFF_CNT);
  int*   deg     = (int*)(ws + OFF_DEG);
  int*   offs    = (int*)(ws + OFF_OFFS);
  int*   cursor  = (int*)(ws + OFF_CURSOR);
  int*   esort   = (int*)(ws + OFF_ESORT);
  float* aggx    = (float*)(ws + OFF_AGGX);
  float* htmp    = (float*)(ws + OFF_HTMP);
  float* xsbuf   = (float*)(ws + OFF_XS);
  float* hbuf    = (float*)(ws + OFF_HBUF);
  float* cbuf    = (float*)(ws + OFF_CBUF);
  float* gates   = (float*)(ws + OFF_GATES);
  float* l2out   = (float*)(ws + OFF_L2OUT);
  unsigned short* whi = (unsigned short*)(ws + OFF_WHI);
  unsigned short* wlo = (unsigned short*)(ws + OFF_WLO);

  hipMemsetAsync(sel_map, 0xFF, (size_t)N * 4, stream);   // -1
  hipMemsetAsync(cnt, 0, 256, stream);
  hipMemsetAsync(deg, 0, NB * 4, stream);
  hipMemsetAsync(cursor, 0, NB * 4, stream);
  hipMemsetAsync(hbuf, 0, (size_t)NB * H * 4, stream);
  hipMemsetAsync(cbuf, 0, (size_t)NB * H * 4, stream);

  wvec_kernel<<<6, 128, 0, stream>>>(gat_W, gat_asrc, gat_adst, wvec);
  mark_roots<<<(NB + 255) / 256, 256, 0, stream>>>(root_idx, aggp, sel_map);
  assign_ids<<<(N + 255) / 256, 256, 0, stream>>>(sel_map, nodelst, cnt);
  convert_weights<<<(WTOT + 255) / 256, 256, 0, stream>>>(lin1_W, gat_W, lstm_Wih,
                                                          lstm_Whh, lin2_W, whi, wlo);

  // lin1: x = [node_feat | send_embd] @ lin1_W + lin1_b  (M=100000, Nn=128, K=256)
  gemm_mfma<<<dim3(2, (N + 255) / 256), 256, 0, stream>>>(
      node_feat, send_embd, nullptr, whi + WOFF_L1, wlo + WOFF_L1,
      lin1_b, x, N, H, 2, 0);

  score_kernel<<<(N + 3) / 4, 256, 0, stream>>>(x, wvec, s_src, s_dst);

  count_edges<<<(E + 255) / 256, 256, 0, stream>>>(edge_idx, sel_map, deg);
  scan_kernel<<<1, 1024, 0, stream>>>(deg, offs);
  scatter_edges2<<<(E + 255) / 256, 256, 0, stream>>>(edge_idx, sel_map, offs, cursor, esort);
  gat_node_kernel<<<NB, 128, 0, stream>>>(nodelst, cnt, offs, esort, x, s_src, s_dst,
                                          aggx, xsbuf);

  for (int i = 0; i < HOPS; i++) {
    // h_tmp_i = tanh(aggx_i @ gat_W[i] + gat_b[i])   (M=4096, Nn=128, K=128)
    gemm_mfma<<<dim3(2, NB / 256), 256, 0, stream>>>(
        aggx + (size_t)i * NB * H, nullptr, nullptr,
        whi + WOFF_GAT + i * 16384, wlo + WOFF_GAT + i * 16384,
        gat_b + (size_t)i * H, htmp, NB, H, 1, 1);
    // gates = [h_tmp | xs | h] @ [Wih;Whh] + b   (M=4096, Nn=512, K=384)
    gemm_mfma<<<dim3(8, NB / 256), 256, 0, stream>>>(
        htmp, xsbuf, hbuf,
        whi + WOFF_CAT + i * 196608, wlo + WOFF_CAT + i * 196608,
        lstm_b + (size_t)i * 512, gates, NB, 512, 3, 0);
    lstm_gate_kernel<<<(NB * H + 255) / 256, 256, 0, stream>>>(gates, cbuf, hbuf, xsbuf);
  }

  // lin2: l2out = xs @ lin2_W + lin2_b   (M=4096, Nn=128, K=128)
  gemm_mfma<<<dim3(2, NB / 256), 256, 0, stream>>>(
      xsbuf, nullptr, nullptr, whi + WOFF_L2, wlo + WOFF_L2,
      lin2_b, l2out, NB, H, 1, 0);

  scatter_out<<<(NB * H + 255) / 256, 256, 0, stream>>>(l2out, sel_map, root_idx, aggp, out);
}